// Round 3
// baseline (1030.423 us; speedup 1.0000x reference)
//
#include <hip/hip_runtime.h>
#include <stdint.h>

#define VOCAB 16384
#define NB 32
#define NTOK 8224      // 32*257
#define MTILES 65      // M tiles of 128 rows
#define MP 8320        // MTILES*128
#define NBLK 256       // N blocks of 64 cols
#define MSPLIT 2
#define TPM 33         // M tiles per split chunk
#define A_TILE 131072  // 128 rows: 8 ksteps * 8 chunks * 2048 B
#define B_TILE 65536   // 64 rows:  8 ksteps * 4 chunks * 2048 B

typedef _Float16 half8 __attribute__((ext_vector_type(8)));
typedef float f4 __attribute__((ext_vector_type(4)));
typedef __attribute__((address_space(1))) const uint32_t* gas_t;
typedef __attribute__((address_space(3))) uint32_t* las_t;

__device__ __forceinline__ void async16(const void* g, void* l) {
    __builtin_amdgcn_global_load_lds((gas_t)g, (las_t)l, 16, 0, 0);
}

__device__ __forceinline__ unsigned long long key64(float v, int idx) {
    unsigned u = __float_as_uint(v);
    u = (u & 0x80000000u) ? ~u : (u | 0x80000000u);
    return ((unsigned long long)u << 32) | (unsigned)(~idx);   // max key = max val, tie -> min idx
}

// ---------- build token matrix tok[NTOK][256] ----------
__global__ __launch_bounds__(256) void k_class(const float* __restrict__ cls, float* __restrict__ tok) {
    int b = blockIdx.x, c = threadIdx.x;
    tok[(b * 257) * 256 + c] = cls[b * 256 + c];
}

__global__ __launch_bounds__(256) void k_patch(const float* __restrict__ patch, float* __restrict__ tok) {
    __shared__ float t[64][65];
    int c0 = blockIdx.x * 64, p0 = blockIdx.y * 64, b = blockIdx.z;
    int tid = threadIdx.x;
    int l = tid & 63, w = tid >> 6;
    const float* src = patch + b * 65536;
#pragma unroll
    for (int i = 0; i < 16; ++i) {
        int row = i * 4 + w;
        t[row][l] = src[(c0 + row) * 256 + p0 + l];
    }
    __syncthreads();
#pragma unroll
    for (int i = 0; i < 16; ++i) {
        int prow = i * 4 + w;
        tok[(b * 257 + 1 + p0 + prow) * 256 + c0 + l] = t[l][prow];
    }
}

// ---------- pack normalized rows -> MFMA fragment-order hi/lo f16 (norms fused) ----------
// layout: [tile][kstep(8)][chunk16rows(cpt)][hi/lo(2)][ lane(64) x 16B ]
__global__ __launch_bounds__(256) void k_pack(const float* __restrict__ src, char* __restrict__ dst,
                                              int nrows, int cpt) {
    __shared__ float t[16][264];
    __shared__ float pr[16][16];
    __shared__ float sn[16];
    int g = blockIdx.x;
    int row0 = g * 16;
    int tid = threadIdx.x;
    int rr = tid >> 4, cb = tid & 15;
    int grow = row0 + rr;
    const float* sp = src + (size_t)grow * 256 + cb * 16;
    float psum = 0.0f;
#pragma unroll
    for (int i = 0; i < 4; ++i) {
        float4 v = (grow < nrows) ? *(const float4*)(sp + i * 4) : make_float4(0.f, 0.f, 0.f, 0.f);
        *(float4*)&t[rr][cb * 16 + i * 4] = v;
        psum += v.x * v.x + v.y * v.y + v.z * v.z + v.w * v.w;
    }
    pr[rr][cb] = psum;
    __syncthreads();
    if (tid < 16) {
        float s = 0.0f;
#pragma unroll
        for (int j = 0; j < 16; ++j) s += pr[tid][j];
        sn[tid] = fmaxf(sqrtf(s), 1e-12f);
    }
    __syncthreads();
    int c = tid & 63, pair = tid >> 6;
    int q = c >> 4, m = c & 15;
    float inv = 1.0f / sn[m];
    char* base = dst + (size_t)(g / cpt) * (size_t)(cpt * 16384) + (size_t)(g % cpt) * 2048;
#pragma unroll
    for (int it = 0; it < 4; ++it) {
        int combo = it * 4 + pair;   // ks(8) x h(2)
        int ks = combo >> 1, h = combo & 1;
        const float* rowp = &t[m][ks * 32 + q * 8];
        half8 o;
#pragma unroll
        for (int j = 0; j < 8; ++j) {
            float v = rowp[j] * inv;
            _Float16 hi = (_Float16)v;
            o[j] = h ? (_Float16)(v - (float)hi) : hi;
        }
        *(half8*)(base + (size_t)ks * (cpt * 2048) + h * 1024 + c * 16) = o;
    }
}

// ---------- sim: B-tile resident in LDS, A streamed, barrier-free K-loop, fused argmax ----------
__global__ __launch_bounds__(512, 4) void k_sim(const char* __restrict__ apk, const char* __restrict__ bpk,
                                                unsigned long long* __restrict__ pbest) {
    __shared__ char Bs[65536];
    int tid = threadIdx.x;
    int ln = tid & 63, w = tid >> 6;
    int by = blockIdx.x, s = blockIdx.y;
    const char* bbase = bpk + (size_t)by * B_TILE;
    // stage full B tile once (64 cols x 256 K, hi+lo)
#pragma unroll
    for (int i = 0; i < 8; ++i) {
        int c = i * 8 + w;                       // 1 KB chunk id, wave-uniform base
        async16(bbase + c * 1024 + ln * 16, Bs + c * 1024);
    }
    __syncthreads();

    const half8* Bf = (const half8*)Bs;
    int t0 = s * TPM;
    int t1 = t0 + TPM; if (t1 > MTILES) t1 = MTILES;

    for (int mt = t0; mt < t1; ++mt) {
        const half8* Af = (const half8*)(apk + (size_t)mt * A_TILE + w * 2048);  // wave = m-chunk (16 rows)
        f4 acc[4];
#pragma unroll
        for (int i = 0; i < 4; ++i) acc[i] = (f4){0.f, 0.f, 0.f, 0.f};
#pragma unroll
        for (int ks = 0; ks < 8; ++ks) {
            half8 ah = Af[ks * 1024 + ln];
            half8 al = Af[ks * 1024 + 64 + ln];
#pragma unroll
            for (int ni = 0; ni < 4; ++ni) {
                half8 bh = Bf[ks * 512 + ni * 128 + ln];
                half8 bl = Bf[ks * 512 + ni * 128 + 64 + ln];
                acc[ni] = __builtin_amdgcn_mfma_f32_16x16x32_f16(ah, bh, acc[ni], 0, 0, 0);
                acc[ni] = __builtin_amdgcn_mfma_f32_16x16x32_f16(ah, bl, acc[ni], 0, 0, 0);
                acc[ni] = __builtin_amdgcn_mfma_f32_16x16x32_f16(al, bh, acc[ni], 0, 0, 0);
            }
        }
        // argmax over this block's 64 cols. C/D: col = ln&15 (n), row = (ln>>4)*4 + r (m)
        int col = ln & 15, quad = ln >> 4;
        int tbase = mt * 128 + w * 16 + quad * 4;
#pragma unroll
        for (int r = 0; r < 4; ++r) {
            float bv = acc[0][r];
            int bn = col;
#pragma unroll
            for (int ni = 1; ni < 4; ++ni) {       // ascending col: strict > keeps first max
                float v = acc[ni][r];
                if (v > bv) { bv = v; bn = ni * 16 + col; }
            }
#pragma unroll
            for (int off = 1; off < 16; off <<= 1) {
                float v2 = __shfl_xor(bv, off);
                int n2 = __shfl_xor(bn, off);
                if (v2 > bv || (v2 == bv && n2 < bn)) { bv = v2; bn = n2; }
            }
            if (col == 0) pbest[(size_t)by * MP + tbase + r] = key64(bv, by * 64 + bn);
        }
    }
}

// ---------- reduce 256 partials/token, class out, loss, used mask, idx ----------
__global__ __launch_bounds__(256) void k_gather(const unsigned long long* __restrict__ pbest,
                                                const float* __restrict__ W, const float* __restrict__ tok,
                                                float* __restrict__ out, int* __restrict__ idxbuf,
                                                float* __restrict__ acc, unsigned int* __restrict__ used) {
    __shared__ unsigned long long red[4][64];
    __shared__ int sidx[64];
    int tid = threadIdx.x;
    int t0 = blockIdx.x * 64;
    int tk = tid & 63, g = tid >> 6;
    unsigned long long best = 0;
    for (int sp = g; sp < NBLK; sp += 4) {          // coalesced: 64 consecutive tokens per row
        unsigned long long v = pbest[(size_t)sp * MP + t0 + tk];
        if (v > best) best = v;
    }
    red[g][tk] = best;
    __syncthreads();
    if (tid < 64) {
        best = red[0][tid];
#pragma unroll
        for (int j = 1; j < 4; ++j) if (red[j][tid] > best) best = red[j][tid];
        sidx[tid] = (int)(~(unsigned)(best & 0xFFFFFFFFull));
    }
    __syncthreads();
    int ln = tid & 63, w = tid >> 6;
    float lsum = 0.0f;
#pragma unroll
    for (int i = 0; i < 16; ++i) {
        int t = t0 + i * 4 + w;
        if (t < NTOK) {
            int bi = sidx[i * 4 + w];
            float4 wv = *(const float4*)&W[(size_t)bi * 256 + ln * 4];
            float4 xv = *(const float4*)&tok[(size_t)t * 256 + ln * 4];
            float dx = wv.x - xv.x, dy = wv.y - xv.y, dz = wv.z - xv.z, dw = wv.w - xv.w;
            lsum += dx * dx + dy * dy + dz * dz + dw * dw;
            if (ln == 0) {
                atomicOr(&used[bi >> 5], 1u << (bi & 31));
                idxbuf[t] = bi;
            }
            int b = t / 257, r = t % 257;
            if (r == 0) *(float4*)&out[b * 256 + ln * 4] = wv;
        }
    }
#pragma unroll
    for (int off = 32; off > 0; off >>= 1) lsum += __shfl_down(lsum, off);
    if (ln == 0) atomicAdd(acc, lsum);
}

// ---------- fhat_patch scatter via LDS transpose (coalesced writes) ----------
__global__ __launch_bounds__(256) void k_scatter(const int* __restrict__ idxbuf, const float* __restrict__ W,
                                                 float* __restrict__ out) {
    __shared__ float t64[64][65];
    __shared__ int sidx[64];
    int c0 = blockIdx.x * 64, p0 = blockIdx.y * 64, b = blockIdx.z;
    int tid = threadIdx.x;
    if (tid < 64) sidx[tid] = idxbuf[b * 257 + 1 + p0 + tid];
    __syncthreads();
    int l = tid & 63, w = tid >> 6;
#pragma unroll
    for (int i = 0; i < 16; ++i) {
        int p = i * 4 + w;
        t64[p][l] = W[(size_t)sidx[p] * 256 + c0 + l];
    }
    __syncthreads();
#pragma unroll
    for (int i = 0; i < 16; ++i) {
        int c = i * 4 + w;
        out[8192 + (size_t)b * 65536 + (size_t)(c0 + c) * 256 + p0 + l] = t64[l][c];
    }
}

__global__ __launch_bounds__(256) void k_final(const unsigned int* __restrict__ used,
                                               const float* __restrict__ acc, float* __restrict__ out) {
    int tid = threadIdx.x;
    int cnt = 0;
    for (int i = tid; i < VOCAB / 32; i += 256) cnt += __popc(used[i]);
#pragma unroll
    for (int off = 32; off > 0; off >>= 1) cnt += __shfl_down(cnt, off);
    __shared__ int p4[4];
    if ((tid & 63) == 0) p4[tid >> 6] = cnt;
    __syncthreads();
    if (tid == 0) {
        int c = p4[0] + p4[1] + p4[2] + p4[3];
        out[8192 + 2097152] = 1.25f * acc[0] / (float)(NTOK * 256);    // vq_loss
        out[8192 + 2097152 + 1] = 100.0f * (float)c / (float)VOCAB;    // vocab_usage
    }
}

extern "C" void kernel_launch(void* const* d_in, const int* in_sizes, int n_in,
                              void* d_out, int out_size, void* d_ws, size_t ws_size,
                              hipStream_t stream) {
    (void)in_sizes; (void)n_in; (void)out_size; (void)ws_size;
    const float* cls = (const float*)d_in[0];
    const float* patch = (const float*)d_in[1];
    const float* W = (const float*)d_in[2];
    float* out = (float*)d_out;

    char* ws = (char*)d_ws;
    float* tok = (float*)ws;                                  // 8224*256 f = 8.42 MB
    char* apk = ws + (size_t)NTOK * 256 * 4;                  // 65*131072  = 8.52 MB
    char* bpk = apk + (size_t)MTILES * A_TILE;                // 256*65536  = 16.78 MB
    unsigned long long* pbest = (unsigned long long*)(bpk + (size_t)NBLK * B_TILE);  // 256*8320*8 = 17.04 MB
    int* idxbuf = (int*)(pbest + (size_t)NBLK * MP);          // 8224 i
    float* acc = (float*)(idxbuf + NTOK);
    unsigned int* used = (unsigned int*)(acc + 1);            // 512 u32

    hipMemsetAsync(acc, 0, (1 + VOCAB / 32) * sizeof(float), stream);

    k_class<<<NB, 256, 0, stream>>>(cls, tok);
    k_patch<<<dim3(4, 4, NB), 256, 0, stream>>>(patch, tok);
    k_pack<<<MTILES * 8, 256, 0, stream>>>(tok, apk, NTOK, 8);
    k_pack<<<VOCAB / 16, 256, 0, stream>>>(W, bpk, VOCAB, 4);
    k_sim<<<dim3(NBLK, MSPLIT), 512, 0, stream>>>(apk, bpk, pbest);
    k_gather<<<(MP / 64), 256, 0, stream>>>(pbest, W, tok, out, idxbuf, acc, used);
    k_scatter<<<dim3(4, 4, NB), 256, 0, stream>>>(idxbuf, W, out);
    k_final<<<1, 256, 0, stream>>>(used, acc, out);
}

// Round 4
// 396.036 us; speedup vs baseline: 2.6018x; 2.6018x over previous
//
#include <hip/hip_runtime.h>
#include <stdint.h>

#define VOCAB 16384
#define NB 32
#define NTOK 8224      // 32*257
#define MTILES 65      // M tiles of 128 rows
#define MP 8320        // MTILES*128
#define NBY 128        // N tiles of 128 cols
#define TILE_BYTES 131072   // 128-row tile: 8 ksteps * 16 KB
#define STEP_BYTES 16384    // per kstep: 8 chunks * 2 (hi/lo) * 1024 B

typedef _Float16 half8 __attribute__((ext_vector_type(8)));
typedef float f4 __attribute__((ext_vector_type(4)));
typedef __attribute__((address_space(1))) const uint32_t* gas_t;
typedef __attribute__((address_space(3))) uint32_t* las_t;

__device__ __forceinline__ void async16(const void* g, void* l) {
    __builtin_amdgcn_global_load_lds((gas_t)g, (las_t)l, 16, 0, 0);
}

__device__ __forceinline__ unsigned long long key64(float v, int idx) {
    unsigned u = __float_as_uint(v);
    u = (u & 0x80000000u) ? ~u : (u | 0x80000000u);
    return ((unsigned long long)u << 32) | (unsigned)(~idx);   // max key = max val, tie -> min idx
}

// ---------- build token matrix tok[NTOK][256] ----------
__global__ __launch_bounds__(256) void k_class(const float* __restrict__ cls, float* __restrict__ tok) {
    int b = blockIdx.x, c = threadIdx.x;
    tok[(b * 257) * 256 + c] = cls[b * 256 + c];
}

__global__ __launch_bounds__(256) void k_patch(const float* __restrict__ patch, float* __restrict__ tok) {
    __shared__ float t[64][65];
    int c0 = blockIdx.x * 64, p0 = blockIdx.y * 64, b = blockIdx.z;
    int tid = threadIdx.x;
    int l = tid & 63, w = tid >> 6;
    const float* src = patch + b * 65536;
#pragma unroll
    for (int i = 0; i < 16; ++i) {
        int row = i * 4 + w;
        t[row][l] = src[(c0 + row) * 256 + p0 + l];
    }
    __syncthreads();
#pragma unroll
    for (int i = 0; i < 16; ++i) {
        int prow = i * 4 + w;
        tok[(b * 257 + 1 + p0 + prow) * 256 + c0 + l] = t[l][prow];
    }
}

// ---------- pack normalized rows -> MFMA fragment-order hi/lo f16 (norms fused) ----------
// layout: [tile128][kstep(8)][chunk16rows(8)][hi/lo(2)][ lane(64) x 16B ]
__global__ __launch_bounds__(256) void k_pack(const float* __restrict__ src, char* __restrict__ dst,
                                              int nrows) {
    __shared__ float t[16][264];
    __shared__ float pr[16][16];
    __shared__ float sn[16];
    int g = blockIdx.x;              // 16-row chunk id
    int row0 = g * 16;
    int tid = threadIdx.x;
    int rr = tid >> 4, cb = tid & 15;
    int grow = row0 + rr;
    const float* sp = src + (size_t)grow * 256 + cb * 16;
    float psum = 0.0f;
#pragma unroll
    for (int i = 0; i < 4; ++i) {
        float4 v = (grow < nrows) ? *(const float4*)(sp + i * 4) : make_float4(0.f, 0.f, 0.f, 0.f);
        *(float4*)&t[rr][cb * 16 + i * 4] = v;
        psum += v.x * v.x + v.y * v.y + v.z * v.z + v.w * v.w;
    }
    pr[rr][cb] = psum;
    __syncthreads();
    if (tid < 16) {
        float s = 0.0f;
#pragma unroll
        for (int j = 0; j < 16; ++j) s += pr[tid][j];
        sn[tid] = fmaxf(sqrtf(s), 1e-12f);
    }
    __syncthreads();
    int c = tid & 63, pair = tid >> 6;
    int q = c >> 4, m = c & 15;
    float inv = 1.0f / sn[m];
    char* base = dst + (size_t)(g >> 3) * TILE_BYTES + (size_t)(g & 7) * 2048;
#pragma unroll
    for (int it = 0; it < 4; ++it) {
        int combo = it * 4 + pair;   // ks(8) x h(2)
        int ks = combo >> 1, h = combo & 1;
        const float* rowp = &t[m][ks * 32 + q * 8];
        half8 o;
#pragma unroll
        for (int j = 0; j < 8; ++j) {
            float v = rowp[j] * inv;
            _Float16 hi = (_Float16)v;
            o[j] = h ? (_Float16)(v - (float)hi) : hi;
        }
        *(half8*)(base + (size_t)ks * STEP_BYTES + h * 1024 + c * 16) = o;
    }
}

// ---------- sim = xn @ WnT, 3-pass split-f16 MFMA, LDS-staged, XCD-swizzled ----------
__global__ __launch_bounds__(256) void k_sim(const char* __restrict__ apk, const char* __restrict__ bpk,
                                             unsigned long long* __restrict__ pbest) {
    __shared__ char lds[32768];      // 16 KB A-kstep + 16 KB B-kstep
    // XCD-aware supertile swizzle: supertile = 13 bx x 8 by (ws 2.75 MB < 4 MB L2/XCD),
    // 80 supertiles striped 10-per-XCD assuming xcd = blockIdx % 8; consecutive
    // supertiles on one XCD share the same by-group (B re-fetched once per group).
    int id = blockIdx.x;             // 0..8319
    int xcd = id & 7, r = id >> 3;   // r 0..1039
    int st = r / 104, within = r % 104;
    int stid = xcd * 10 + st;        // 0..79
    int sx = stid % 5, sy = stid / 5;
    int bx = sx * 13 + within % 13;  // 0..64
    int by = sy * 8 + within / 13;   // 0..127

    int tid = threadIdx.x;
    int ln = tid & 63, wv = tid >> 6;
    int mh = wv >> 1, nh = wv & 1;
    const char* abase = apk + (size_t)bx * TILE_BYTES;
    const char* bbase = bpk + (size_t)by * TILE_BYTES;

    f4 acc[4][4];
#pragma unroll
    for (int i = 0; i < 4; ++i)
#pragma unroll
        for (int j = 0; j < 4; ++j) acc[i][j] = (f4){0.f, 0.f, 0.f, 0.f};

    // stage kstep 0
#pragma unroll
    for (int i = 0; i < 8; ++i) {
        int c = wv * 8 + i;
        const char* g = (c < 16 ? abase + (c << 10) : bbase + ((c - 16) << 10)) + (ln << 4);
        async16(g, lds + (c << 10));
    }

    for (int ks = 0; ks < 8; ++ks) {
        __syncthreads();             // staged tile visible
        const half8* Af = (const half8*)lds;
        const half8* Bf = (const half8*)(lds + 16384);
        half8 ah[4], al[4], bh[4], bl[4];
#pragma unroll
        for (int mi = 0; mi < 4; ++mi) {
            int c8 = (mh * 4 + mi) * 2;
            ah[mi] = Af[c8 * 64 + ln];
            al[mi] = Af[(c8 + 1) * 64 + ln];
        }
#pragma unroll
        for (int ni = 0; ni < 4; ++ni) {
            int c8 = (nh * 4 + ni) * 2;
            bh[ni] = Bf[c8 * 64 + ln];
            bl[ni] = Bf[(c8 + 1) * 64 + ln];
        }
        __syncthreads();             // frag reads done; safe to overwrite
        if (ks < 7) {
            const char* a2 = abase + (ks + 1) * STEP_BYTES;
            const char* b2 = bbase + (ks + 1) * STEP_BYTES;
#pragma unroll
            for (int i = 0; i < 8; ++i) {
                int c = wv * 8 + i;
                const char* g = (c < 16 ? a2 + (c << 10) : b2 + ((c - 16) << 10)) + (ln << 4);
                async16(g, lds + (c << 10));
            }
        }
#pragma unroll
        for (int mi = 0; mi < 4; ++mi)
#pragma unroll
            for (int ni = 0; ni < 4; ++ni) {
                acc[mi][ni] = __builtin_amdgcn_mfma_f32_16x16x32_f16(ah[mi], bh[ni], acc[mi][ni], 0, 0, 0);
                acc[mi][ni] = __builtin_amdgcn_mfma_f32_16x16x32_f16(ah[mi], bl[ni], acc[mi][ni], 0, 0, 0);
                acc[mi][ni] = __builtin_amdgcn_mfma_f32_16x16x32_f16(al[mi], bh[ni], acc[mi][ni], 0, 0, 0);
            }
    }

    // fused argmax.  C/D layout: col = ln&15 (n), row = (ln>>4)*4 + reg (m)
    int col = ln & 15, quad = ln >> 4;
    unsigned long long* skey = (unsigned long long*)lds;   // 256 u64
    __syncthreads();
#pragma unroll
    for (int mi = 0; mi < 4; ++mi)
#pragma unroll
        for (int rg = 0; rg < 4; ++rg) {
            float bv = acc[mi][0][rg];
            int bn = nh * 64 + col;
#pragma unroll
            for (int ni = 1; ni < 4; ++ni) {       // ascending col: > keeps first max
                float v = acc[mi][ni][rg];
                if (v > bv) { bv = v; bn = nh * 64 + ni * 16 + col; }
            }
#pragma unroll
            for (int off = 1; off < 16; off <<= 1) {
                float v2 = __shfl_xor(bv, off);
                int n2 = __shfl_xor(bn, off);
                if (v2 > bv || (v2 == bv && n2 < bn)) { bv = v2; bn = n2; }
            }
            if (col == 0) {
                int ml = mh * 64 + mi * 16 + quad * 4 + rg;
                skey[ml * 2 + nh] = key64(bv, by * 128 + bn);
            }
        }
    __syncthreads();
    if (tid < 128) {
        unsigned long long a = skey[tid * 2], b = skey[tid * 2 + 1];
        pbest[(size_t)by * MP + bx * 128 + tid] = (a > b) ? a : b;
    }
}

// ---------- reduce 128 partials/token, class out, loss, used mask, idx ----------
__global__ __launch_bounds__(256) void k_gather(const unsigned long long* __restrict__ pbest,
                                                const float* __restrict__ W, const float* __restrict__ tok,
                                                float* __restrict__ out, int* __restrict__ idxbuf,
                                                float* __restrict__ acc, unsigned int* __restrict__ used) {
    __shared__ unsigned long long red[4][64];
    __shared__ int sidx[64];
    int tid = threadIdx.x;
    int t0 = blockIdx.x * 64;
    int tk = tid & 63, g = tid >> 6;
    unsigned long long best = 0;
    for (int sp = g; sp < NBY; sp += 4) {          // coalesced: 64 consecutive tokens per row
        unsigned long long v = pbest[(size_t)sp * MP + t0 + tk];
        if (v > best) best = v;
    }
    red[g][tk] = best;
    __syncthreads();
    if (tid < 64) {
        best = red[0][tid];
#pragma unroll
        for (int j = 1; j < 4; ++j) if (red[j][tid] > best) best = red[j][tid];
        sidx[tid] = (int)(~(unsigned)(best & 0xFFFFFFFFull));
    }
    __syncthreads();
    int ln = tid & 63, w = tid >> 6;
    float lsum = 0.0f;
#pragma unroll
    for (int i = 0; i < 16; ++i) {
        int t = t0 + i * 4 + w;
        if (t < NTOK) {
            int bi = sidx[i * 4 + w];
            float4 wv = *(const float4*)&W[(size_t)bi * 256 + ln * 4];
            float4 xv = *(const float4*)&tok[(size_t)t * 256 + ln * 4];
            float dx = wv.x - xv.x, dy = wv.y - xv.y, dz = wv.z - xv.z, dw = wv.w - xv.w;
            lsum += dx * dx + dy * dy + dz * dz + dw * dw;
            if (ln == 0) {
                atomicOr(&used[bi >> 5], 1u << (bi & 31));
                idxbuf[t] = bi;
            }
            int b = t / 257, r = t % 257;
            if (r == 0) *(float4*)&out[b * 256 + ln * 4] = wv;
        }
    }
#pragma unroll
    for (int off = 32; off > 0; off >>= 1) lsum += __shfl_down(lsum, off);
    if (ln == 0) atomicAdd(acc, lsum);
}

// ---------- fhat_patch scatter via LDS transpose (coalesced writes) ----------
__global__ __launch_bounds__(256) void k_scatter(const int* __restrict__ idxbuf, const float* __restrict__ W,
                                                 float* __restrict__ out) {
    __shared__ float t64[64][65];
    __shared__ int sidx[64];
    int c0 = blockIdx.x * 64, p0 = blockIdx.y * 64, b = blockIdx.z;
    int tid = threadIdx.x;
    if (tid < 64) sidx[tid] = idxbuf[b * 257 + 1 + p0 + tid];
    __syncthreads();
    int l = tid & 63, w = tid >> 6;
#pragma unroll
    for (int i = 0; i < 16; ++i) {
        int p = i * 4 + w;
        t64[p][l] = W[(size_t)sidx[p] * 256 + c0 + l];
    }
    __syncthreads();
#pragma unroll
    for (int i = 0; i < 16; ++i) {
        int c = i * 4 + w;
        out[8192 + (size_t)b * 65536 + (size_t)(c0 + c) * 256 + p0 + l] = t64[l][c];
    }
}

__global__ __launch_bounds__(256) void k_final(const unsigned int* __restrict__ used,
                                               const float* __restrict__ acc, float* __restrict__ out) {
    int tid = threadIdx.x;
    int cnt = 0;
    for (int i = tid; i < VOCAB / 32; i += 256) cnt += __popc(used[i]);
#pragma unroll
    for (int off = 32; off > 0; off >>= 1) cnt += __shfl_down(cnt, off);
    __shared__ int p4[4];
    if ((tid & 63) == 0) p4[tid >> 6] = cnt;
    __syncthreads();
    if (tid == 0) {
        int c = p4[0] + p4[1] + p4[2] + p4[3];
        out[8192 + 2097152] = 1.25f * acc[0] / (float)(NTOK * 256);    // vq_loss
        out[8192 + 2097152 + 1] = 100.0f * (float)c / (float)VOCAB;    // vocab_usage
    }
}

extern "C" void kernel_launch(void* const* d_in, const int* in_sizes, int n_in,
                              void* d_out, int out_size, void* d_ws, size_t ws_size,
                              hipStream_t stream) {
    (void)in_sizes; (void)n_in; (void)out_size; (void)ws_size;
    const float* cls = (const float*)d_in[0];
    const float* patch = (const float*)d_in[1];
    const float* W = (const float*)d_in[2];
    float* out = (float*)d_out;

    char* ws = (char*)d_ws;
    float* tok = (float*)ws;                                  // 8224*256 f = 8.42 MB
    char* apk = ws + (size_t)NTOK * 256 * 4;                  // 65*131072  = 8.52 MB
    char* bpk = apk + (size_t)MTILES * TILE_BYTES;            // 128*131072 = 16.78 MB
    unsigned long long* pbest = (unsigned long long*)(bpk + (size_t)NBY * TILE_BYTES);  // 128*8320*8 = 8.5 MB
    int* idxbuf = (int*)(pbest + (size_t)NBY * MP);           // 8224 i
    float* acc = (float*)(idxbuf + NTOK);
    unsigned int* used = (unsigned int*)(acc + 1);            // 512 u32

    hipMemsetAsync(acc, 0, (1 + VOCAB / 32) * sizeof(float), stream);

    k_class<<<NB, 256, 0, stream>>>(cls, tok);
    k_patch<<<dim3(4, 4, NB), 256, 0, stream>>>(patch, tok);
    k_pack<<<MTILES * 8, 256, 0, stream>>>(tok, apk, NTOK);
    k_pack<<<VOCAB / 16, 256, 0, stream>>>(W, bpk, VOCAB);
    k_sim<<<MTILES * NBY, 256, 0, stream>>>(apk, bpk, pbest);
    k_gather<<<(MP / 64), 256, 0, stream>>>(pbest, W, tok, out, idxbuf, acc, used);
    k_scatter<<<dim3(4, 4, NB), 256, 0, stream>>>(idxbuf, W, out);
    k_final<<<1, 256, 0, stream>>>(used, acc, out);
}

// Round 5
// 303.886 us; speedup vs baseline: 3.3908x; 1.3032x over previous
//
#include <hip/hip_runtime.h>
#include <stdint.h>

#define VOCAB 16384
#define NB 32
#define NTOK 8224      // 32*257
#define MTILES 65      // M tiles of 128 rows
#define MP 8320        // MTILES*128
#define NBY 128        // N tiles of 128 cols
#define TILE_BYTES 65536    // 128 rows x 256 K x 2B f16 (hi plane only)
#define PHASE_BYTES 16384   // K64 phase
#define NLOSS 2056          // loss partial blocks (NTOK/4)
#define MWIN 2.2e-3f        // rigorous |sim_f16 - sim_fp32| window (2*margin)

typedef _Float16 half8 __attribute__((ext_vector_type(8)));
typedef float f4 __attribute__((ext_vector_type(4)));
typedef __attribute__((address_space(1))) const uint32_t* gas_t;
typedef __attribute__((address_space(3))) uint32_t* las_t;

__device__ __forceinline__ void async16(const void* g, void* l) {
    __builtin_amdgcn_global_load_lds((gas_t)g, (las_t)l, 16, 0, 0);
}

__device__ __forceinline__ unsigned long long key64(float v, int idx) {
    unsigned u = __float_as_uint(v);
    u = (u & 0x80000000u) ? ~u : (u | 0x80000000u);
    return ((unsigned long long)u << 32) | (unsigned)(~idx);   // order: val desc, idx asc
}

__device__ __forceinline__ float keyval(unsigned long long k) {
    unsigned u = (unsigned)(k >> 32);
    u = (u & 0x80000000u) ? (u & 0x7fffffffu) : ~u;
    return __uint_as_float(u);
}

__device__ __forceinline__ void merge2(unsigned long long& k1, unsigned long long& k2,
                                       unsigned long long p1, unsigned long long p2) {
    unsigned long long lo = k1 < p1 ? k1 : p1;           // top-2 of {k1,k2,p1,p2}, k2<=k1, p2<=p1
    k1 = k1 > p1 ? k1 : p1;
    unsigned long long m2 = k2 > p2 ? k2 : p2;
    k2 = lo > m2 ? lo : m2;
}

// ---------- build token matrix tok[NTOK][256] ----------
__global__ __launch_bounds__(256) void k_class(const float* __restrict__ cls, float* __restrict__ tok) {
    int b = blockIdx.x, c = threadIdx.x;
    tok[(b * 257) * 256 + c] = cls[b * 256 + c];
}

__global__ __launch_bounds__(256) void k_patch(const float* __restrict__ patch, float* __restrict__ tok) {
    __shared__ float t[64][65];
    int c0 = blockIdx.x * 64, p0 = blockIdx.y * 64, b = blockIdx.z;
    int tid = threadIdx.x;
    int l = tid & 63, w = tid >> 6;
    const float* src = patch + b * 65536;
#pragma unroll
    for (int i = 0; i < 16; ++i) {
        int row = i * 4 + w;
        t[row][l] = src[(c0 + row) * 256 + p0 + l];
    }
    __syncthreads();
#pragma unroll
    for (int i = 0; i < 16; ++i) {
        int prow = i * 4 + w;
        tok[(b * 257 + 1 + p0 + prow) * 256 + c0 + l] = t[l][prow];
    }
}

// ---------- pack normalized rows -> f16 hi plane, MFMA fragment order; saves norms ----------
// layout: [tile128][k32(8)][chunk16(8)][ lane(64) x 16B ]
__global__ __launch_bounds__(256) void k_pack(const float* __restrict__ src, char* __restrict__ dst,
                                              float* __restrict__ norms, int nrows) {
    __shared__ float t[16][264];
    __shared__ float pr[16][16];
    __shared__ float sn[16];
    int g = blockIdx.x;              // 16-row chunk id
    int row0 = g * 16;
    int tid = threadIdx.x;
    int rr = tid >> 4, cb = tid & 15;
    int grow = row0 + rr;
    const float* sp = src + (size_t)grow * 256 + cb * 16;
    float psum = 0.0f;
#pragma unroll
    for (int i = 0; i < 4; ++i) {
        float4 v = (grow < nrows) ? *(const float4*)(sp + i * 4) : make_float4(0.f, 0.f, 0.f, 0.f);
        *(float4*)&t[rr][cb * 16 + i * 4] = v;
        psum += v.x * v.x + v.y * v.y + v.z * v.z + v.w * v.w;
    }
    pr[rr][cb] = psum;
    __syncthreads();
    if (tid < 16) {
        float s = 0.0f;
#pragma unroll
        for (int j = 0; j < 16; ++j) s += pr[tid][j];
        float nv = fmaxf(sqrtf(s), 1e-12f);
        sn[tid] = nv;
        norms[row0 + tid] = nv;
    }
    __syncthreads();
    int c = tid & 63, pair = tid >> 6;   // pair 0..3
    int m = c & 15, jb = (c >> 4) * 8;
    float inv = 1.0f / sn[m];
    char* base = dst + (size_t)(g >> 3) * TILE_BYTES + (size_t)(g & 7) * 1024 + c * 16;
#pragma unroll
    for (int it = 0; it < 2; ++it) {
        int k32 = it * 4 + pair;         // 0..7
        const float* rowp = &t[m][k32 * 32 + jb];
        half8 o;
#pragma unroll
        for (int j = 0; j < 8; ++j) o[j] = (_Float16)(rowp[j] * inv);
        *(half8*)(base + (size_t)k32 * 8192) = o;
    }
}

// ---------- sim: single-pass f16 MFMA, LDS-staged, XCD-swizzled, top-2/block argmax ----------
__global__ __launch_bounds__(256) void k_sim(const char* __restrict__ apk, const char* __restrict__ bpk,
                                             unsigned long long* __restrict__ pb) {
    __shared__ char lds[32768];      // 16 KB A-phase + 16 KB B-phase (K64)
    // XCD-aware supertile swizzle (R4-proven: FETCH 602->90 MB)
    int id = blockIdx.x;             // 0..8319
    int xcd = id & 7, r = id >> 3;
    int st = r / 104, within = r % 104;
    int stid = xcd * 10 + st;        // 0..79
    int sx = stid % 5, sy = stid / 5;
    int bx = sx * 13 + within % 13;  // 0..64
    int by = sy * 8 + within / 13;   // 0..127

    int tid = threadIdx.x;
    int ln = tid & 63, wv = tid >> 6;
    int mh = wv >> 1, nh = wv & 1;
    const char* abase = apk + (size_t)bx * TILE_BYTES;
    const char* bbase = bpk + (size_t)by * TILE_BYTES;

    f4 acc[4][4];
#pragma unroll
    for (int i = 0; i < 4; ++i)
#pragma unroll
        for (int j = 0; j < 4; ++j) acc[i][j] = (f4){0.f, 0.f, 0.f, 0.f};

    // stage phase 0 (A 16 KB + B 16 KB)
#pragma unroll
    for (int i = 0; i < 8; ++i) {
        int c = wv * 8 + i;          // 0..31
        const char* g = (c < 16 ? abase + (c << 10) : bbase + ((c - 16) << 10)) + (ln << 4);
        async16(g, lds + (c << 10));
    }

    for (int p = 0; p < 4; ++p) {
        __syncthreads();             // staged phase visible
        half8 ah[2][4], bh[2][4];
#pragma unroll
        for (int s = 0; s < 2; ++s) {
            const half8* Af = (const half8*)(lds + s * 8192);
            const half8* Bf = (const half8*)(lds + 16384 + s * 8192);
#pragma unroll
            for (int mi = 0; mi < 4; ++mi) ah[s][mi] = Af[(mh * 4 + mi) * 64 + ln];
#pragma unroll
            for (int ni = 0; ni < 4; ++ni) bh[s][ni] = Bf[(nh * 4 + ni) * 64 + ln];
        }
        __syncthreads();             // frag reads done; safe to overwrite
        if (p < 3) {
            const char* a2 = abase + (p + 1) * PHASE_BYTES;
            const char* b2 = bbase + (p + 1) * PHASE_BYTES;
#pragma unroll
            for (int i = 0; i < 8; ++i) {
                int c = wv * 8 + i;
                const char* g = (c < 16 ? a2 + (c << 10) : b2 + ((c - 16) << 10)) + (ln << 4);
                async16(g, lds + (c << 10));
            }
        }
#pragma unroll
        for (int s = 0; s < 2; ++s)
#pragma unroll
            for (int mi = 0; mi < 4; ++mi)
#pragma unroll
                for (int ni = 0; ni < 4; ++ni)
                    acc[mi][ni] = __builtin_amdgcn_mfma_f32_16x16x32_f16(ah[s][mi], bh[s][ni], acc[mi][ni], 0, 0, 0);
    }

    // top-2 per token row over this block's 128 cols.
    // C/D: col = ln&15 (n), row = (ln>>4)*4 + reg (m)
    int col = ln & 15, quad = ln >> 4;
    unsigned long long* s1 = (unsigned long long*)lds;          // [128][2]
    unsigned long long* s2 = (unsigned long long*)(lds + 2048); // [128][2]
    __syncthreads();
#pragma unroll
    for (int mi = 0; mi < 4; ++mi)
#pragma unroll
        for (int rg = 0; rg < 4; ++rg) {
            unsigned long long k1, k2;
            {
                unsigned long long ka = key64(acc[mi][0][rg], by * 128 + nh * 64 + col);
                unsigned long long kb = key64(acc[mi][1][rg], by * 128 + nh * 64 + 16 + col);
                k1 = ka > kb ? ka : kb;
                k2 = ka > kb ? kb : ka;
#pragma unroll
                for (int ni = 2; ni < 4; ++ni) {
                    unsigned long long kc = key64(acc[mi][ni][rg], by * 128 + nh * 64 + ni * 16 + col);
                    if (kc > k1) { k2 = k1; k1 = kc; }
                    else if (kc > k2) { k2 = kc; }
                }
            }
#pragma unroll
            for (int off = 1; off < 16; off <<= 1) {
                unsigned long long p1 = __shfl_xor(k1, off);
                unsigned long long p2 = __shfl_xor(k2, off);
                merge2(k1, k2, p1, p2);
            }
            if (col == 0) {
                int row = mh * 64 + mi * 16 + quad * 4 + rg;
                s1[row * 2 + nh] = k1;
                s2[row * 2 + nh] = k2;
            }
        }
    __syncthreads();
    if (tid < 128) {
        unsigned long long k1 = s1[tid * 2], k2 = s2[tid * 2];
        merge2(k1, k2, s1[tid * 2 + 1], s2[tid * 2 + 1]);
        ulonglong2 v; v.x = k1; v.y = k2;
        ((ulonglong2*)pb)[((size_t)bx * 128 + tid) * 128 + by] = v;
    }
}

// ---------- per token: G over block tops, exact fp32 verify of candidates, outputs ----------
__global__ __launch_bounds__(256) void k_gather(const unsigned long long* __restrict__ pb,
                                                const float* __restrict__ W, const float* __restrict__ tok,
                                                const float* __restrict__ ntok, const float* __restrict__ nw,
                                                float* __restrict__ out, int* __restrict__ idxbuf,
                                                float* __restrict__ lossbuf, unsigned int* __restrict__ used) {
    __shared__ float lp[4];
    int tid = threadIdx.x;
    int t = blockIdx.x * 4 + (tid >> 6);
    int ln = tid & 63, w = tid >> 6;
    const ulonglong2* pv = (const ulonglong2*)pb;
    ulonglong2 ea = pv[(size_t)t * 128 + ln];
    ulonglong2 eb = pv[(size_t)t * 128 + 64 + ln];
    unsigned long long g = ea.x > eb.x ? ea.x : eb.x;
#pragma unroll
    for (int off = 1; off < 64; off <<= 1) {
        unsigned long long o = __shfl_xor(g, off);
        if (o > g) g = o;
    }
    float T = keyval(g) - MWIN;
    f4 xv = *(const f4*)&tok[(size_t)t * 256 + ln * 4];
    float nt = ntok[t];
    unsigned long long k4[4] = {ea.x, ea.y, eb.x, eb.y};
    float bestv = -3.0f;
    int besti = 0x7fffffff;
#pragma unroll
    for (int gi = 0; gi < 4; ++gi) {
        unsigned long long mask = __ballot(keyval(k4[gi]) >= T);
        while (mask) {
            int src = __ffsll((unsigned long long)mask) - 1;
            mask &= mask - 1;
            unsigned long long ck = __shfl(k4[gi], src);
            int ci = (int)(~(unsigned)(ck & 0xffffffffu));
            f4 wc = *(const f4*)&W[(size_t)ci * 256 + ln * 4];
            float d = xv.x * wc.x + xv.y * wc.y + xv.z * wc.z + xv.w * wc.w;
#pragma unroll
            for (int off = 1; off < 64; off <<= 1) d += __shfl_xor(d, off);
            float sim = d / (nt * nw[ci]);
            if (sim > bestv || (sim == bestv && ci < besti)) { bestv = sim; besti = ci; }
        }
    }
    int bi = besti;
    f4 wr = *(const f4*)&W[(size_t)bi * 256 + ln * 4];
    float dx = wr.x - xv.x, dy = wr.y - xv.y, dz = wr.z - xv.z, dw = wr.w - xv.w;
    float ls = dx * dx + dy * dy + dz * dz + dw * dw;
#pragma unroll
    for (int off = 1; off < 64; off <<= 1) ls += __shfl_xor(ls, off);
    if (ln == 0) {
        lp[w] = ls;
        atomicOr(&used[bi >> 5], 1u << (bi & 31));
        idxbuf[t] = bi;
    }
    if (t % 257 == 0) {
        int b = t / 257;
        *(f4*)&out[b * 256 + ln * 4] = wr;           // fhat_class
    }
    __syncthreads();
    if (tid == 0) lossbuf[blockIdx.x] = lp[0] + lp[1] + lp[2] + lp[3];
}

// ---------- fhat_patch scatter via LDS transpose (coalesced writes) ----------
__global__ __launch_bounds__(256) void k_scatter(const int* __restrict__ idxbuf, const float* __restrict__ W,
                                                 float* __restrict__ out) {
    __shared__ float t64[64][65];
    __shared__ int sidx[64];
    int c0 = blockIdx.x * 64, p0 = blockIdx.y * 64, b = blockIdx.z;
    int tid = threadIdx.x;
    if (tid < 64) sidx[tid] = idxbuf[b * 257 + 1 + p0 + tid];
    __syncthreads();
    int l = tid & 63, w = tid >> 6;
#pragma unroll
    for (int i = 0; i < 16; ++i) {
        int p = i * 4 + w;
        t64[p][l] = W[(size_t)sidx[p] * 256 + c0 + l];
    }
    __syncthreads();
#pragma unroll
    for (int i = 0; i < 16; ++i) {
        int c = i * 4 + w;
        out[8192 + (size_t)b * 65536 + (size_t)(c0 + c) * 256 + p0 + l] = t64[l][c];
    }
}

__global__ __launch_bounds__(256) void k_final(const unsigned int* __restrict__ used,
                                               const float* __restrict__ lossbuf, float* __restrict__ out) {
    int tid = threadIdx.x;
    int cnt = 0;
    float ls = 0.0f;
    for (int i = tid; i < VOCAB / 32; i += 256) cnt += __popc(used[i]);
    for (int i = tid; i < NLOSS; i += 256) ls += lossbuf[i];
#pragma unroll
    for (int off = 32; off > 0; off >>= 1) {
        cnt += __shfl_down(cnt, off);
        ls += __shfl_down(ls, off);
    }
    __shared__ int p4[4];
    __shared__ float f4s[4];
    if ((tid & 63) == 0) { p4[tid >> 6] = cnt; f4s[tid >> 6] = ls; }
    __syncthreads();
    if (tid == 0) {
        int c = p4[0] + p4[1] + p4[2] + p4[3];
        float l = f4s[0] + f4s[1] + f4s[2] + f4s[3];
        out[8192 + 2097152] = 1.25f * l / (float)(NTOK * 256);         // vq_loss
        out[8192 + 2097152 + 1] = 100.0f * (float)c / (float)VOCAB;    // vocab_usage
    }
}

extern "C" void kernel_launch(void* const* d_in, const int* in_sizes, int n_in,
                              void* d_out, int out_size, void* d_ws, size_t ws_size,
                              hipStream_t stream) {
    (void)in_sizes; (void)n_in; (void)out_size; (void)ws_size;
    const float* cls = (const float*)d_in[0];
    const float* patch = (const float*)d_in[1];
    const float* W = (const float*)d_in[2];
    float* out = (float*)d_out;

    char* ws = (char*)d_ws;
    float* tok = (float*)ws;                                   // 8224*256 f = 8.42 MB
    char* apk = ws + (size_t)NTOK * 256 * 4;                   // 65*65536  = 4.26 MB
    char* bpk = apk + (size_t)MTILES * TILE_BYTES;             // 128*65536 = 8.39 MB
    unsigned long long* pb = (unsigned long long*)(bpk + (size_t)NBY * TILE_BYTES);  // 8320*128*16 B = 17 MB
    float* ntokv = (float*)(pb + (size_t)MP * NBY * 2);        // 8320 f
    float* nwv = ntokv + MP;                                   // 16384 f
    float* lossbuf = nwv + VOCAB;                              // 2056 f
    int* idxbuf = (int*)(lossbuf + NLOSS);                     // 8224 i
    unsigned int* used = (unsigned int*)(idxbuf + NTOK);       // 512 u32

    hipMemsetAsync(used, 0, (VOCAB / 32) * sizeof(unsigned int), stream);

    k_class<<<NB, 256, 0, stream>>>(cls, tok);
    k_patch<<<dim3(4, 4, NB), 256, 0, stream>>>(patch, tok);
    k_pack<<<MTILES * 8, 256, 0, stream>>>(tok, apk, ntokv, NTOK);
    k_pack<<<VOCAB / 16, 256, 0, stream>>>(W, bpk, nwv, VOCAB);
    k_sim<<<MTILES * NBY, 256, 0, stream>>>(apk, bpk, pb);
    k_gather<<<NLOSS, 256, 0, stream>>>(pb, W, tok, ntokv, nwv, out, idxbuf, lossbuf, used);
    k_scatter<<<dim3(4, 4, NB), 256, 0, stream>>>(idxbuf, W, out);
    k_final<<<1, 256, 0, stream>>>(used, lossbuf, out);
}